// Round 8
// baseline (1288.526 us; speedup 1.0000x reference)
//
#include <hip/hip_runtime.h>

// GNN encoder + GRU decoder. R8 = R7 (29 launches, MFMA step body) + weight
// PREFETCH BURST. R7 measured: every dispatch re-fetches the ~1MB fp16 weight
// pool from HBM (FETCH 2.57MB/dispatch, every step) at 63 GB/s latency-bound
// demand misses = ~41us of the 50us dispatch. Cross-XCD L2s are invalidated at
// dispatch boundaries, so weights never stay hot. Fix: at kernel start each
// block streams a 1/16 slice of g_wf16 with 8 independent dwordx4 loads/thread
// (slice = bid>>3: round-robin XCD assignment -> each XCD's 16 blocks cover
// all slices), turning the scatter into a full-concurrency burst.

#define NJ 32
#define ROWS 512
#define TSTEPS 25
#define LDH 132          // f32 row stride
#define LDK 264          // half row stride (256-wide)
#define LDE 168          // half row stride, encoder input
#define LDG 520          // half row stride, gates

typedef _Float16 half_t;
typedef __attribute__((ext_vector_type(8))) _Float16 half8;
typedef __attribute__((ext_vector_type(8))) short short8;
typedef __attribute__((ext_vector_type(4))) float f32x4;

#define OFF_ENC_W1T 0          // [256 j][160 k]
#define OFF_ENC_W2T 40960      // [128 j][256 k]
#define OFF_PE_W1T  73728      // [512 j][128 k]  (j<256: P, j>=256: Q)
#define OFF_PE_W2T  139264     // [128 j][256 k]
#define OFF_PN_W1T  172032     // [256 j][128 k]
#define OFF_PN_W2T  204800     // [128 j][256 k]
#define OFF_DE_W1T  237568     // [512 j][128 k]
#define OFF_DE_W2T  303104     // [128 j][256 k]
#define OFF_WGT     335872     // [512 j][288 k]
#define WTOTAL      483328     // halves (966,656 B)

__device__ __align__(16) half_t g_wf16[WTOTAL];
__device__ __align__(16) float g_hbuf[2 * 16 * 32 * LDH];   // ping-pong h
__device__ float g_sink;

__device__ __forceinline__ half8 h8zero() {
    half8 z;
    #pragma unroll
    for (int e = 0; e < 8; ++e) z[e] = (half_t)0.f;
    return z;
}
__device__ __forceinline__ half8 relu8(half8 x) {
    short8 s = *(short8*)&x;
    short8 m = s >> 15;
    s = s & ~m;
    return *(half8*)&s;
}
__device__ __forceinline__ half8 frag_from_f32(const float* base) {
    f32x4 a = *(const f32x4*)base;
    f32x4 c = *(const f32x4*)(base + 4);
    half8 h;
    #pragma unroll
    for (int e = 0; e < 4; ++e) { h[e] = (half_t)a[e]; h[4 + e] = (half_t)c[e]; }
    return h;
}
#define MFMA(a, b, c) __builtin_amdgcn_mfma_f32_16x16x32_f16((a), (b), (c), 0, 0, 0)

// ---- prefetch burst: block sweeps slice (bid>>3) of the weight pool --------
// 3776 f32x4 per slice; 512 threads x 8 independent loads -> max MLP.
__device__ __forceinline__ float weight_prefetch(int bid, int tid) {
    const int slice = (bid >> 3) & 15;
    const f32x4* p = (const f32x4*)(g_wf16 + (size_t)slice * (WTOTAL / 16));
    f32x4 s = (f32x4)(0.f);
    #pragma unroll
    for (int u = 0; u < 8; ++u) {
        const int i = tid + u * 512;
        if (i < 3776) s += p[i];
    }
    return s[0] + s[1] + s[2] + s[3];
}

// ---------------- weight conversion (once per call) ----------
__global__ void convert_kernel(const float* __restrict__ enc_w1, const float* __restrict__ enc_w2,
                               const float* __restrict__ pe_w1, const float* __restrict__ pe_w2,
                               const float* __restrict__ pn_w1, const float* __restrict__ pn_w2,
                               const float* __restrict__ de_w1, const float* __restrict__ de_w2,
                               const float* __restrict__ w_hr, const float* __restrict__ w_hi,
                               const float* __restrict__ w_hn, const float* __restrict__ w_ir,
                               const float* __restrict__ w_ii, const float* __restrict__ w_in) {
    const int idx = blockIdx.x * 256 + threadIdx.x;
    if (idx >= WTOTAL) return;
    float v = 0.f;
    if (idx < OFF_ENC_W2T) {
        int o = idx, j = o / 160, k = o - j * 160;
        v = (k < 150) ? enc_w1[k * 256 + j] : 0.f;
    } else if (idx < OFF_PE_W1T) {
        int o = idx - OFF_ENC_W2T, j = o >> 8, k = o & 255;
        v = enc_w2[k * 128 + j];
    } else if (idx < OFF_PE_W2T) {
        int o = idx - OFF_PE_W1T, j = o >> 7, k = o & 127;
        v = pe_w1[(k + ((j >= 256) ? 128 : 0)) * 256 + (j & 255)];
    } else if (idx < OFF_PN_W1T) {
        int o = idx - OFF_PE_W2T, j = o >> 8, k = o & 255;
        v = pe_w2[k * 128 + j];
    } else if (idx < OFF_PN_W2T) {
        int o = idx - OFF_PN_W1T, j = o >> 7, k = o & 127;
        v = pn_w1[k * 256 + j];
    } else if (idx < OFF_DE_W1T) {
        int o = idx - OFF_PN_W2T, j = o >> 8, k = o & 255;
        v = pn_w2[k * 128 + j];
    } else if (idx < OFF_DE_W2T) {
        int o = idx - OFF_DE_W1T, j = o >> 7, k = o & 127;
        v = de_w1[(k + ((j >= 256) ? 128 : 0)) * 256 + (j & 255)];
    } else if (idx < OFF_WGT) {
        int o = idx - OFF_DE_W2T, j = o >> 8, k = o & 255;
        v = de_w2[k * 128 + j];
    } else {
        int o = idx - OFF_WGT, j = o / 288, k = o - j * 288;
        int g = j >> 7, jj = j & 127;
        if (g == 0)
            v = (k < 128) ? w_ir[k * 128 + jj] : (k < 256) ? w_hr[(k - 128) * 128 + jj]
              : (k < 259) ? w_ir[(128 + k - 256) * 128 + jj] : 0.f;
        else if (g == 1)
            v = (k < 128) ? w_ii[k * 128 + jj] : (k < 256) ? w_hi[(k - 128) * 128 + jj]
              : (k < 259) ? w_ii[(128 + k - 256) * 128 + jj] : 0.f;
        else if (g == 2)
            v = (k < 128) ? w_in[k * 128 + jj]
              : (k >= 256 && k < 259) ? w_in[(128 + k - 256) * 128 + jj] : 0.f;
        else
            v = (k >= 128 && k < 256) ? w_hn[(k - 128) * 128 + jj] : 0.f;
    }
    g_wf16[idx] = (half_t)v;
}

// ---------------- encoder MLP (grid 128, each block writes own 4 rows) ------
__global__ void __launch_bounds__(512, 2)
encoder_kernel(const float* __restrict__ enc_in,
               const float* __restrict__ enc_b1, const float* __restrict__ enc_b2) {
    const int bid = blockIdx.x;
    const int b = bid & 15;
    const int sub = bid >> 4;
    const int tid = threadIdx.x;
    const int wave = tid >> 6;
    const int lane = tid & 63;
    const int m16 = lane & 15, quad = lane >> 4;
    const int r0 = sub * 4;

    const float pf = weight_prefetch(bid, tid);

    __shared__ __align__(16) half_t s_enc[32 * LDE];
    __shared__ __align__(16) half_t s_hid[32 * LDK];

    for (int i = tid; i < 32 * LDE; i += 512) {
        const int s = i / LDE, k = i - s * LDE;
        s_enc[i] = (half_t)((k < 150) ? enc_in[((size_t)b * 32 + s) * 150 + k] : 0.f);
    }
    __syncthreads();
    // l1: [32x256], K=160
    #pragma unroll
    for (int i = 0; i < 4; ++i) {
        const int ti = wave + i * 8;
        const int nt = ti & 15, mt = ti >> 4;
        f32x4 acc = (f32x4)(0.f);
        #pragma unroll
        for (int k = 0; k < 5; ++k) {
            half8 a  = *(const half8*)&s_enc[(mt * 16 + m16) * LDE + k * 32 + quad * 8];
            half8 bf = *(const half8*)&g_wf16[OFF_ENC_W1T + (nt * 16 + m16) * 160 + k * 32 + quad * 8];
            acc = MFMA(a, bf, acc);
        }
        const int j = nt * 16 + m16;
        const float bj = enc_b1[j];
        #pragma unroll
        for (int g = 0; g < 4; ++g)
            s_hid[(mt * 16 + quad * 4 + g) * LDK + j] = (half_t)fmaxf(acc[g] + bj, 0.f);
    }
    __syncthreads();
    // l2: [32x128], K=256; keep own 4 rows -> g_hbuf parity 0
    float* h0 = g_hbuf + (size_t)b * 32 * LDH;
    #pragma unroll
    for (int i = 0; i < 2; ++i) {
        const int ti = wave + i * 8;
        const int nt = ti & 7, mt = ti >> 3;
        f32x4 acc = (f32x4)(0.f);
        #pragma unroll
        for (int k = 0; k < 8; ++k) {
            half8 a  = *(const half8*)&s_hid[(mt * 16 + m16) * LDK + k * 32 + quad * 8];
            half8 bf = *(const half8*)&g_wf16[OFF_ENC_W2T + (nt * 16 + m16) * 256 + k * 32 + quad * 8];
            acc = MFMA(a, bf, acc);
        }
        if (mt == (sub >> 2) && quad == (sub & 3)) {
            const int j = nt * 16 + m16;
            const float bj = enc_b2[j];
            #pragma unroll
            for (int g = 0; g < 4; ++g)
                h0[(r0 + g) * LDH + j] = fmaxf(acc[g] + bj, 0.f);
        }
    }
    if (pf == 1.0e38f) g_sink = pf;   // defeat DCE of the prefetch (never true)
}

// ---------------- one step: P/Q -> edge -> (node MLP | GRU) -----------------
// grid 128 (16 batches x 8 subs, 4 receivers each), 512 threads.
template <int IS_DEC>
__global__ void __launch_bounds__(512, 2)
pass_kernel(int parity, int t,
            const float* __restrict__ b1, const float* __restrict__ b2,
            const float* __restrict__ pn_b1, const float* __restrict__ pn_b2,
            const float* __restrict__ b_ir, const float* __restrict__ b_ii,
            const float* __restrict__ b_in,
            const float* __restrict__ dec_in, float* __restrict__ out) {
    const int bid = blockIdx.x;
    const int b = bid & 15;
    const int sub = bid >> 4;
    const int tid = threadIdx.x;
    const int wave = tid >> 6;
    const int lane = tid & 63;
    const int m16 = lane & 15, quad = lane >> 4;
    const int r0 = sub * 4;
    const int qmt = sub >> 2, qquad = sub & 3;

    const float pf = weight_prefetch(bid, tid);

    __shared__ __align__(16) unsigned char smem[105600];
    half_t* s_w2T = (half_t*)smem;                    // [128][LDK]
    half_t* s_P   = (half_t*)(smem + 67584);          // [32][LDK]
    half_t* s_Qb  = (half_t*)(smem + 84480);          // [4][LDK]
    float*  s_h   = (float*)(smem + 86592);           // [32][LDH]
    float*  s_msg = (float*)(smem + 103488);          // [4][LDH]
    half_t* s_hid   = s_P;
    half_t* s_gates = s_P;

    // stage w2T (edge layer-2 weights) into LDS
    for (int i = tid; i < 128 * 32; i += 512) {
        const int row = i >> 5, c = i & 31;
        *(half8*)&s_w2T[row * LDK + c * 8] =
            *(const half8*)&g_wf16[(IS_DEC ? OFF_DE_W2T : OFF_PE_W2T) + row * 256 + c * 8];
    }
    // load h
    {
        const float* hsrc = g_hbuf + ((size_t)parity * 16 + b) * 32 * LDH;
        for (int i = tid; i < 32 * 32; i += 512) {
            const int row = i >> 5, c = i & 31;
            *(f32x4*)&s_h[row * LDH + c * 4] = *(const f32x4*)&hsrc[row * LDH + c * 4];
        }
    }
    __syncthreads();

    // ---- P (full) / Qb (own rows) ----
    {
        const half_t* w1T = g_wf16 + (IS_DEC ? OFF_DE_W1T : OFF_PE_W1T);
        half8 a[2][4];
        #pragma unroll
        for (int mt = 0; mt < 2; ++mt)
            #pragma unroll
            for (int k = 0; k < 4; ++k)
                a[mt][k] = frag_from_f32(&s_h[(mt * 16 + m16) * LDH + k * 32 + quad * 8]);
        #pragma unroll
        for (int i = 0; i < 6; ++i) {
            const int ti = wave + 8 * i;          // 0..47
            const bool isQ = ti >= 32;
            const int nt = isQ ? (ti - 16) : (ti & 15);
            const int mt = isQ ? qmt : (ti >> 4);
            f32x4 acc = (f32x4)(0.f);
            #pragma unroll
            for (int k = 0; k < 4; ++k) {
                half8 bf = *(const half8*)&w1T[(nt * 16 + m16) * 128 + k * 32 + quad * 8];
                acc = MFMA(a[mt][k], bf, acc);
            }
            const int j = nt * 16 + m16;
            if (!isQ) {
                #pragma unroll
                for (int g = 0; g < 4; ++g)
                    s_P[(mt * 16 + quad * 4 + g) * LDK + j] = (half_t)acc[g];
            } else if (quad == qquad) {
                const float bj = b1[j - 256];
                #pragma unroll
                for (int g = 0; g < 4; ++g)
                    s_Qb[g * LDK + (j - 256)] = (half_t)(acc[g] + bj);
            }
        }
    }
    __syncthreads();

    // ---- edge layer2 + relu + mean (2 waves per receiver) ----
    {
        const int rl = wave >> 1;
        const int r = r0 + rl;
        const int nh = wave & 1;
        half8 qb[8];
        #pragma unroll
        for (int k = 0; k < 8; ++k)
            qb[k] = *(const half8*)&s_Qb[rl * LDK + k * 32 + quad * 8];
        half8 A[2][8];
        #pragma unroll
        for (int mt = 0; mt < 2; ++mt) {
            const int s = mt * 16 + m16;
            const bool dz = (s == r);
            #pragma unroll
            for (int k = 0; k < 8; ++k) {
                half8 pv = *(const half8*)&s_P[s * LDK + k * 32 + quad * 8];
                half8 hv = relu8(pv + qb[k]);
                A[mt][k] = dz ? h8zero() : hv;
            }
        }
        #pragma unroll
        for (int ni = 0; ni < 4; ++ni) {
            const int n = nh * 4 + ni;
            f32x4 acc0 = (f32x4)(0.f), acc1 = (f32x4)(0.f);
            #pragma unroll
            for (int k = 0; k < 8; ++k) {
                half8 bf = *(const half8*)&s_w2T[(n * 16 + m16) * LDK + k * 32 + quad * 8];
                acc0 = MFMA(A[0][k], bf, acc0);
                acc1 = MFMA(A[1][k], bf, acc1);
            }
            const float b2n = b2[n * 16 + m16];
            float pp = 0.f;
            #pragma unroll
            for (int g = 0; g < 4; ++g)
                pp += fmaxf(acc0[g] + b2n, 0.f) + fmaxf(acc1[g] + b2n, 0.f);
            pp += __shfl_xor(pp, 16);
            pp += __shfl_xor(pp, 32);
            if (quad == 0)
                s_msg[rl * LDH + n * 16 + m16] = (pp - fmaxf(b2n, 0.f)) * (1.f / 31.f);
        }
    }
    __syncthreads();

    float* h_next = g_hbuf + ((size_t)(parity ^ 1) * 16 + b) * 32 * LDH;

    if (!IS_DEC) {
        // ---- node MLP on own 4 msg rows (M=4) ----
        const int mrow = (m16 < 4) ? m16 : 0;
        half8 afr[4];
        #pragma unroll
        for (int k = 0; k < 4; ++k)
            afr[k] = frag_from_f32(&s_msg[mrow * LDH + k * 32 + quad * 8]);
        #pragma unroll
        for (int i = 0; i < 2; ++i) {
            const int nt = wave + i * 8;
            f32x4 acc = (f32x4)(0.f);
            #pragma unroll
            for (int k = 0; k < 4; ++k) {
                half8 bf = *(const half8*)&g_wf16[OFF_PN_W1T + (nt * 16 + m16) * 128 + k * 32 + quad * 8];
                acc = MFMA(afr[k], bf, acc);
            }
            if (quad == 0) {
                const int j = nt * 16 + m16;
                const float bj = pn_b1[j];
                #pragma unroll
                for (int g = 0; g < 4; ++g)
                    s_hid[g * LDK + j] = (half_t)fmaxf(acc[g] + bj, 0.f);
            }
        }
        __syncthreads();
        half8 ah[8];
        #pragma unroll
        for (int k = 0; k < 8; ++k)
            ah[k] = *(const half8*)&s_hid[mrow * LDK + k * 32 + quad * 8];
        {
            const int nt = wave;
            f32x4 acc = (f32x4)(0.f);
            #pragma unroll
            for (int k = 0; k < 8; ++k) {
                half8 bf = *(const half8*)&g_wf16[OFF_PN_W2T + (nt * 16 + m16) * 256 + k * 32 + quad * 8];
                acc = MFMA(ah[k], bf, acc);
            }
            if (quad == 0) {
                const int j = nt * 16 + m16;
                const float bj = pn_b2[j];
                #pragma unroll
                for (int g = 0; g < 4; ++g)
                    h_next[(r0 + g) * LDH + j] = fmaxf(acc[g] + bj, 0.f);
            }
        }
    } else {
        // ---- GRU gate GEMM (M=4, own rows) ----
        const float* dec_row = dec_in + ((size_t)(t * 16 + b) * 32 + r0) * 3;
        const int mrow = (m16 < 4) ? m16 : 0;
        half8 afr[9];
        #pragma unroll
        for (int k = 0; k < 4; ++k)
            afr[k] = frag_from_f32(&s_msg[mrow * LDH + k * 32 + quad * 8]);
        #pragma unroll
        for (int k = 0; k < 4; ++k)
            afr[4 + k] = frag_from_f32(&s_h[(r0 + mrow) * LDH + k * 32 + quad * 8]);
        {
            half8 tt = h8zero();
            if (quad == 0 && m16 < 4) {
                tt[0] = (half_t)dec_row[mrow * 3 + 0];
                tt[1] = (half_t)dec_row[mrow * 3 + 1];
                tt[2] = (half_t)dec_row[mrow * 3 + 2];
            }
            afr[8] = tt;
        }
        #pragma unroll
        for (int i = 0; i < 4; ++i) {
            const int nt = wave + i * 8;       // 0..31
            const int g = nt >> 3;
            f32x4 acc = (f32x4)(0.f);
            #pragma unroll
            for (int k = 0; k < 9; ++k) {
                const bool use = (g <= 1) || (g == 2 && (k < 4 || k == 8))
                                          || (g == 3 && k >= 4 && k < 8);
                if (use) {
                    half8 bf = *(const half8*)&g_wf16[OFF_WGT + (nt * 16 + m16) * 288 + k * 32 + quad * 8];
                    acc = MFMA(afr[k], bf, acc);
                }
            }
            if (quad == 0) {
                const int j = nt * 16 + m16;
                #pragma unroll
                for (int gg = 0; gg < 4; ++gg)
                    s_gates[gg * LDG + j] = (half_t)acc[gg];
            }
        }
        __syncthreads();
        // ---- GRU epilogue ----
        {
            const int ri = tid >> 7;           // 0..3
            const int j = tid & 127;
            const int r = r0 + ri;
            const float rsv = (float)s_gates[ri * LDG + j] + b_ir[j];
            const float isv = (float)s_gates[ri * LDG + 128 + j] + b_ii[j];
            const float nsv = (float)s_gates[ri * LDG + 256 + j] + b_in[j];
            const float hnv = (float)s_gates[ri * LDG + 384 + j];
            const float rr = 1.f / (1.f + __expf(-rsv));
            const float ii = 1.f / (1.f + __expf(-isv));
            const float nn = tanhf(nsv + rr * hnv);
            const float hnew = (1.f - ii) * nn + ii * s_h[r * LDH + j];
            h_next[r * LDH + j] = hnew;
            out[(size_t)t * ROWS * 128 + ((size_t)b * 32 + r) * 128 + j] = hnew;
            if (t == TSTEPS - 1)
                out[(size_t)TSTEPS * ROWS * 128 + ((size_t)b * 32 + r) * 128 + j] = hnew;
        }
    }
    if (pf == 1.0e38f) g_sink = pf;   // defeat DCE of the prefetch (never true)
}

extern "C" void kernel_launch(void* const* d_in, const int* in_sizes, int n_in,
                              void* d_out, int out_size, void* d_ws, size_t ws_size,
                              hipStream_t stream) {
    const float* enc_in = (const float*)d_in[0];
    const float* dec_in = (const float*)d_in[1];
    // d_in[2], d_in[3] = R, S incidence: fully-connected, not needed.
    const float* enc_w1 = (const float*)d_in[4];
    const float* enc_b1 = (const float*)d_in[5];
    const float* enc_w2 = (const float*)d_in[6];
    const float* enc_b2 = (const float*)d_in[7];
    const float* pe_w1 = (const float*)d_in[8];
    const float* pe_b1 = (const float*)d_in[9];
    const float* pe_w2 = (const float*)d_in[10];
    const float* pe_b2 = (const float*)d_in[11];
    const float* pn_w1 = (const float*)d_in[12];
    const float* pn_b1 = (const float*)d_in[13];
    const float* pn_w2 = (const float*)d_in[14];
    const float* pn_b2 = (const float*)d_in[15];
    const float* de_w1 = (const float*)d_in[16];
    const float* de_b1 = (const float*)d_in[17];
    const float* de_w2 = (const float*)d_in[18];
    const float* de_b2 = (const float*)d_in[19];
    const float* w_hr = (const float*)d_in[20];
    const float* w_hi = (const float*)d_in[21];
    const float* w_hn = (const float*)d_in[22];
    const float* w_ir = (const float*)d_in[23];
    const float* b_ir = (const float*)d_in[24];
    const float* w_ii = (const float*)d_in[25];
    const float* b_ii = (const float*)d_in[26];
    const float* w_in = (const float*)d_in[27];
    const float* b_in = (const float*)d_in[28];
    (void)d_ws; (void)ws_size; (void)in_sizes; (void)n_in;

    convert_kernel<<<(WTOTAL + 255) / 256, 256, 0, stream>>>(
        enc_w1, enc_w2, pe_w1, pe_w2, pn_w1, pn_w2, de_w1, de_w2,
        w_hr, w_hi, w_hn, w_ir, w_ii, w_in);

    encoder_kernel<<<128, 512, 0, stream>>>(enc_in, enc_b1, enc_b2);

    int p = 0;
    for (int pass = 0; pass < 2; ++pass) {
        pass_kernel<0><<<128, 512, 0, stream>>>(p, 0, pe_b1, pe_b2, pn_b1, pn_b2,
                                                nullptr, nullptr, nullptr,
                                                nullptr, nullptr);
        p ^= 1;
    }
    float* out = (float*)d_out;
    for (int t = 0; t < TSTEPS; ++t) {
        pass_kernel<1><<<128, 512, 0, stream>>>(p, t, de_b1, de_b2, nullptr, nullptr,
                                                b_ir, b_ii, b_in, dec_in, out);
        p ^= 1;
    }
}

// Round 9
// 770.923 us; speedup vs baseline: 1.6714x; 1.6714x over previous
//
#include <hip/hip_runtime.h>

// GNN encoder + GRU decoder. R9: wide-grid lean kernels.
// Evidence: per-step time tracks grid width (R4 512blk ~13us disp; R5 16blk
// 55us/step; R7/R8 128blk 48us/step, unchanged by L2 warming) -> latency-bound
// serial chains, fixable only by concurrency. New structure per step:
//   edge_kernel: 512 blocks (one per (b,r)), 256 thr, ~27KB LDS, 4 blk/CU.
//     Recomputes P/Q in-block via MFMA (redundant but ~2us chip-wide), then
//     edge layer-2 MFMA + relu + mean -> g_msg.
//   gru_kernel: 64 blocks (b x 4 gate-slices), M=32 N=128 K=288 MFMA; WGT
//     columns reordered so each 128-wide n-tile = all 4 gates for 32 j's ->
//     epilogue block-local. node_kernel (32 blocks) for passing rounds.
// Sync = launch boundaries (cheapest, validated). 56 launches.

#define TSTEPS 25

typedef _Float16 half_t;
typedef __attribute__((ext_vector_type(8))) _Float16 half8;
typedef __attribute__((ext_vector_type(8))) short short8;
typedef __attribute__((ext_vector_type(4))) float f32x4;

#define OFF_ENC_W1T 0          // [256 j][160 k]
#define OFF_ENC_W2T 40960      // [128 j][256 k]
#define OFF_PE_W1T  73728      // [512 j][128 k]  (j<256: P, j>=256: Q)
#define OFF_PE_W2T  139264     // [128 j][256 k]
#define OFF_PN_W1T  172032     // [256 j][128 k]
#define OFF_PN_W2T  204800     // [128 j][256 k]
#define OFF_DE_W1T  237568     // [512 j][128 k]
#define OFF_DE_W2T  303104     // [128 j][256 k]
#define OFF_WGT     335872     // [512 c][288 k], c reordered (see convert)
#define WTOTAL      483328

__device__ __align__(16) half_t g_wf16[WTOTAL];
__device__ __align__(16) float g_hbuf[2 * 512 * 128];   // ping-pong h, plain
__device__ __align__(16) float g_msg[512 * 128];

__device__ __forceinline__ half8 h8zero() {
    half8 z;
    #pragma unroll
    for (int e = 0; e < 8; ++e) z[e] = (half_t)0.f;
    return z;
}
__device__ __forceinline__ half8 relu8(half8 x) {
    short8 s = *(short8*)&x;
    short8 m = s >> 15;
    s = s & ~m;
    return *(half8*)&s;
}
#define MFMA(a, b, c) __builtin_amdgcn_mfma_f32_16x16x32_f16((a), (b), (c), 0, 0, 0)

// ---------------- weight conversion (once per call) ----------
__global__ void convert_kernel(const float* __restrict__ enc_w1, const float* __restrict__ enc_w2,
                               const float* __restrict__ pe_w1, const float* __restrict__ pe_w2,
                               const float* __restrict__ pn_w1, const float* __restrict__ pn_w2,
                               const float* __restrict__ de_w1, const float* __restrict__ de_w2,
                               const float* __restrict__ w_hr, const float* __restrict__ w_hi,
                               const float* __restrict__ w_hn, const float* __restrict__ w_ir,
                               const float* __restrict__ w_ii, const float* __restrict__ w_in) {
    const int idx = blockIdx.x * 256 + threadIdx.x;
    if (idx >= WTOTAL) return;
    float v = 0.f;
    if (idx < OFF_ENC_W2T) {
        int o = idx, j = o / 160, k = o - j * 160;
        v = (k < 150) ? enc_w1[k * 256 + j] : 0.f;
    } else if (idx < OFF_PE_W1T) {
        int o = idx - OFF_ENC_W2T, j = o >> 8, k = o & 255;
        v = enc_w2[k * 128 + j];
    } else if (idx < OFF_PE_W2T) {
        int o = idx - OFF_PE_W1T, j = o >> 7, k = o & 127;
        v = pe_w1[(k + ((j >= 256) ? 128 : 0)) * 256 + (j & 255)];
    } else if (idx < OFF_PN_W1T) {
        int o = idx - OFF_PE_W2T, j = o >> 8, k = o & 255;
        v = pe_w2[k * 128 + j];
    } else if (idx < OFF_PN_W2T) {
        int o = idx - OFF_PN_W1T, j = o >> 7, k = o & 127;
        v = pn_w1[k * 256 + j];
    } else if (idx < OFF_DE_W1T) {
        int o = idx - OFF_PN_W2T, j = o >> 8, k = o & 255;
        v = pn_w2[k * 128 + j];
    } else if (idx < OFF_DE_W2T) {
        int o = idx - OFF_DE_W1T, j = o >> 7, k = o & 127;
        v = de_w1[(k + ((j >= 256) ? 128 : 0)) * 256 + (j & 255)];
    } else if (idx < OFF_WGT) {
        int o = idx - OFF_DE_W2T, j = o >> 8, k = o & 255;
        v = de_w2[k * 128 + j];
    } else {
        // WGT': col c -> (nt = c>>7, cc = c&127, grp = cc>>5, j = nt*32 + (cc&31))
        int o = idx - OFF_WGT, c = o / 288, k = o - c * 288;
        int grp = (c >> 5) & 3, j = ((c >> 7) << 5) | (c & 31);
        if (grp == 0)
            v = (k < 128) ? w_ir[k * 128 + j] : (k < 256) ? w_hr[(k - 128) * 128 + j]
              : (k < 259) ? w_ir[(128 + k - 256) * 128 + j] : 0.f;
        else if (grp == 1)
            v = (k < 128) ? w_ii[k * 128 + j] : (k < 256) ? w_hi[(k - 128) * 128 + j]
              : (k < 259) ? w_ii[(128 + k - 256) * 128 + j] : 0.f;
        else if (grp == 2)
            v = (k < 128) ? w_in[k * 128 + j]
              : (k >= 256 && k < 259) ? w_in[(128 + k - 256) * 128 + j] : 0.f;
        else
            v = (k >= 128 && k < 256) ? w_hn[(k - 128) * 128 + j] : 0.f;
    }
    g_wf16[idx] = (half_t)v;
}

// ---------------- encoder MLP (grid 128, each block writes own 4 rows) ------
__global__ void __launch_bounds__(512, 2)
encoder_kernel(const float* __restrict__ enc_in,
               const float* __restrict__ enc_b1, const float* __restrict__ enc_b2) {
    const int b = blockIdx.x & 15;
    const int sub = blockIdx.x >> 4;
    const int tid = threadIdx.x;
    const int wave = tid >> 6;
    const int lane = tid & 63;
    const int m16 = lane & 15, quad = lane >> 4;
    const int r0 = sub * 4;

    __shared__ __align__(16) half_t s_enc[32 * 168];
    __shared__ __align__(16) half_t s_hid[32 * 264];

    for (int i = tid; i < 32 * 168; i += 512) {
        const int s = i / 168, k = i - s * 168;
        s_enc[i] = (half_t)((k < 150) ? enc_in[((size_t)b * 32 + s) * 150 + k] : 0.f);
    }
    __syncthreads();
    #pragma unroll
    for (int i = 0; i < 4; ++i) {
        const int ti = wave + i * 8;
        const int nt = ti & 15, mt = ti >> 4;
        f32x4 acc = (f32x4)(0.f);
        #pragma unroll
        for (int k = 0; k < 5; ++k) {
            half8 a  = *(const half8*)&s_enc[(mt * 16 + m16) * 168 + k * 32 + quad * 8];
            half8 bf = *(const half8*)&g_wf16[OFF_ENC_W1T + (nt * 16 + m16) * 160 + k * 32 + quad * 8];
            acc = MFMA(a, bf, acc);
        }
        const int j = nt * 16 + m16;
        const float bj = enc_b1[j];
        #pragma unroll
        for (int g = 0; g < 4; ++g)
            s_hid[(mt * 16 + quad * 4 + g) * 264 + j] = (half_t)fmaxf(acc[g] + bj, 0.f);
    }
    __syncthreads();
    float* h0 = g_hbuf + (size_t)b * 32 * 128;
    #pragma unroll
    for (int i = 0; i < 2; ++i) {
        const int ti = wave + i * 8;
        const int nt = ti & 7, mt = ti >> 3;
        f32x4 acc = (f32x4)(0.f);
        #pragma unroll
        for (int k = 0; k < 8; ++k) {
            half8 a  = *(const half8*)&s_hid[(mt * 16 + m16) * 264 + k * 32 + quad * 8];
            half8 bf = *(const half8*)&g_wf16[OFF_ENC_W2T + (nt * 16 + m16) * 256 + k * 32 + quad * 8];
            acc = MFMA(a, bf, acc);
        }
        if (mt == (sub >> 2) && quad == (sub & 3)) {
            const int j = nt * 16 + m16;
            const float bj = enc_b2[j];
            #pragma unroll
            for (int g = 0; g < 4; ++g)
                h0[(r0 + g) * 128 + j] = fmaxf(acc[g] + bj, 0.f);
        }
    }
}

// ---------------- edge kernel: one block per (b, r) -------------------------
// Computes P (32x256) + Q(row r) via MFMA in-block, then edge layer-2 + mean.
template <int IS_DEC>
__global__ void __launch_bounds__(256, 4)
edge_kernel(int parity, const float* __restrict__ b1, const float* __restrict__ b2) {
    const int b = blockIdx.x >> 5;
    const int r = blockIdx.x & 31;
    const int tid = threadIdx.x;
    const int wave = tid >> 6;
    const int lane = tid & 63;
    const int m16 = lane & 15, quad = lane >> 4;

    __shared__ __align__(16) half_t s_hh[32 * 136];   // h as halves
    __shared__ __align__(16) half_t s_P[32 * 264];
    __shared__ __align__(16) half_t s_Qb[264];

    // stage h[b] -> halves
    {
        const float* hsrc = g_hbuf + (size_t)parity * 512 * 128 + (size_t)b * 32 * 128;
        const int i = tid * 16;
        const int row = i >> 7, col = i & 127;
        const float* sp = hsrc + row * 128 + col;
        half8 h0, h1;
        #pragma unroll
        for (int e = 0; e < 8; ++e) { h0[e] = (half_t)sp[e]; h1[e] = (half_t)sp[8 + e]; }
        *(half8*)&s_hh[row * 136 + col] = h0;
        *(half8*)&s_hh[row * 136 + col + 8] = h1;
    }
    __syncthreads();

    // P/Q MFMA: 48 tasks (32 P + 16 Q) over 4 waves
    {
        const half_t* w1T = g_wf16 + (IS_DEC ? OFF_DE_W1T : OFF_PE_W1T);
        const int rmt = r >> 4, rloc = r & 15;
        for (int i = 0; i < 12; ++i) {
            const int ti = wave + 4 * i;          // 0..47
            const bool isQ = ti >= 32;
            const int nt = isQ ? (ti - 32) : (ti & 15);
            const int mt = isQ ? rmt : (ti >> 4);
            const int brow = isQ ? (nt + 16) : nt;
            f32x4 acc = (f32x4)(0.f);
            #pragma unroll
            for (int k = 0; k < 4; ++k) {
                half8 a = *(const half8*)&s_hh[(mt * 16 + m16) * 136 + k * 32 + quad * 8];
                half8 bf = *(const half8*)&w1T[(brow * 16 + m16) * 128 + k * 32 + quad * 8];
                acc = MFMA(a, bf, acc);
            }
            const int j = nt * 16 + m16;
            if (!isQ) {
                #pragma unroll
                for (int g = 0; g < 4; ++g)
                    s_P[(mt * 16 + quad * 4 + g) * 264 + j] = (half_t)acc[g];
            } else {
                const float bj = b1[j];
                #pragma unroll
                for (int g = 0; g < 4; ++g)
                    if (quad * 4 + g == rloc) s_Qb[j] = (half_t)(acc[g] + bj);
            }
        }
    }
    __syncthreads();

    // edge layer-2 + relu + mean: 8 n-tiles over 4 waves (2 each)
    {
        const half_t* w2T = g_wf16 + (IS_DEC ? OFF_DE_W2T : OFF_PE_W2T);
        half8 qb[8];
        #pragma unroll
        for (int k = 0; k < 8; ++k)
            qb[k] = *(const half8*)&s_Qb[k * 32 + quad * 8];
        half8 A[2][8];
        #pragma unroll
        for (int mt = 0; mt < 2; ++mt) {
            const int s = mt * 16 + m16;
            const bool dz = (s == r);
            #pragma unroll
            for (int k = 0; k < 8; ++k) {
                half8 pv = *(const half8*)&s_P[s * 264 + k * 32 + quad * 8];
                half8 hv = relu8(pv + qb[k]);
                A[mt][k] = dz ? h8zero() : hv;
            }
        }
        #pragma unroll
        for (int ni = 0; ni < 2; ++ni) {
            const int nt = wave * 2 + ni;
            f32x4 acc0 = (f32x4)(0.f), acc1 = (f32x4)(0.f);
            #pragma unroll
            for (int k = 0; k < 8; ++k) {
                half8 bf = *(const half8*)&w2T[(nt * 16 + m16) * 256 + k * 32 + quad * 8];
                acc0 = MFMA(A[0][k], bf, acc0);
                acc1 = MFMA(A[1][k], bf, acc1);
            }
            const float b2n = b2[nt * 16 + m16];
            float pp = 0.f;
            #pragma unroll
            for (int g = 0; g < 4; ++g)
                pp += fmaxf(acc0[g] + b2n, 0.f) + fmaxf(acc1[g] + b2n, 0.f);
            pp += __shfl_xor(pp, 16);
            pp += __shfl_xor(pp, 32);
            if (quad == 0)
                g_msg[((size_t)b * 32 + r) * 128 + nt * 16 + m16] =
                    (pp - fmaxf(b2n, 0.f)) * (1.f / 31.f);
        }
    }
}

// ---------------- node MLP (passing rounds): grid 32, 16 rows/block ---------
__global__ void __launch_bounds__(256, 4)
node_kernel(int parity_out, const float* __restrict__ pn_b1, const float* __restrict__ pn_b2) {
    const int mt16 = blockIdx.x;          // rows mt16*16 .. +15
    const int tid = threadIdx.x;
    const int wave = tid >> 6;
    const int lane = tid & 63;
    const int m16 = lane & 15, quad = lane >> 4;

    __shared__ __align__(16) half_t s_A[16 * 136];
    __shared__ __align__(16) half_t s_H[16 * 264];

    {
        const int i = tid * 8;            // 2048 msg floats
        const int row = i >> 7, col = i & 127;
        const float* sp = g_msg + ((size_t)mt16 * 16 + row) * 128 + col;
        half8 h0;
        #pragma unroll
        for (int e = 0; e < 8; ++e) h0[e] = (half_t)sp[e];
        *(half8*)&s_A[row * 136 + col] = h0;
    }
    __syncthreads();
    // layer1: N=256, K=128: 16 n-tiles / 4 waves
    #pragma unroll
    for (int i = 0; i < 4; ++i) {
        const int nt = wave + 4 * i;
        f32x4 acc = (f32x4)(0.f);
        #pragma unroll
        for (int k = 0; k < 4; ++k) {
            half8 a = *(const half8*)&s_A[m16 * 136 + k * 32 + quad * 8];
            half8 bf = *(const half8*)&g_wf16[OFF_PN_W1T + (nt * 16 + m16) * 128 + k * 32 + quad * 8];
            acc = MFMA(a, bf, acc);
        }
        const int j = nt * 16 + m16;
        const float bj = pn_b1[j];
        #pragma unroll
        for (int g = 0; g < 4; ++g)
            s_H[(quad * 4 + g) * 264 + j] = (half_t)fmaxf(acc[g] + bj, 0.f);
    }
    __syncthreads();
    // layer2: N=128, K=256: 8 n-tiles / 4 waves
    float* h_next = g_hbuf + (size_t)parity_out * 512 * 128;
    #pragma unroll
    for (int i = 0; i < 2; ++i) {
        const int nt = wave + 4 * i;      // 0..7
        f32x4 acc = (f32x4)(0.f);
        #pragma unroll
        for (int k = 0; k < 8; ++k) {
            half8 a = *(const half8*)&s_H[m16 * 264 + k * 32 + quad * 8];
            half8 bf = *(const half8*)&g_wf16[OFF_PN_W2T + (nt * 16 + m16) * 256 + k * 32 + quad * 8];
            acc = MFMA(a, bf, acc);
        }
        const int j = nt * 16 + m16;
        const float bj = pn_b2[j];
        #pragma unroll
        for (int g = 0; g < 4; ++g)
            h_next[((size_t)mt16 * 16 + quad * 4 + g) * 128 + j] = fmaxf(acc[g] + bj, 0.f);
    }
}

// ---------------- GRU kernel: grid 64 = (b 0..15) x (nt 0..3) ---------------
// Block: 32 rows of batch b, gate j-slice nt*32..+31 (all 4 gate groups).
__global__ void __launch_bounds__(256, 4)
gru_kernel(int parity, int t,
           const float* __restrict__ b_ir, const float* __restrict__ b_ii,
           const float* __restrict__ b_in,
           const float* __restrict__ dec_in, float* __restrict__ out) {
    const int b = blockIdx.x >> 2;
    const int nt = blockIdx.x & 3;
    const int tid = threadIdx.x;
    const int wave = tid >> 6;
    const int lane = tid & 63;
    const int m16 = lane & 15, quad = lane >> 4;
    const float* hsrc = g_hbuf + (size_t)parity * 512 * 128 + (size_t)b * 32 * 128;

    __shared__ __align__(16) half_t s_A[32 * 296];   // [msg|h|dec|0] halves
    __shared__ __align__(16) half_t s_g[32 * 136];   // gates for this slice

    // stage A
    {
        const int i = tid * 16;
        const int row = i >> 7, col = i & 127;
        const float* mp = g_msg + ((size_t)b * 32 + row) * 128 + col;
        const float* hp = hsrc + row * 128 + col;
        half8 m0, m1, h0, h1;
        #pragma unroll
        for (int e = 0; e < 8; ++e) {
            m0[e] = (half_t)mp[e]; m1[e] = (half_t)mp[8 + e];
            h0[e] = (half_t)hp[e]; h1[e] = (half_t)hp[8 + e];
        }
        *(half8*)&s_A[row * 296 + col] = m0;
        *(half8*)&s_A[row * 296 + col + 8] = m1;
        *(half8*)&s_A[row * 296 + 128 + col] = h0;
        *(half8*)&s_A[row * 296 + 128 + col + 8] = h1;
    }
    for (int i = tid; i < 32 * 32; i += 256) {
        const int row = i >> 5, c = i & 31;
        s_A[row * 296 + 256 + c] = (c < 3)
            ? (half_t)dec_in[(((size_t)t * 16 + b) * 32 + row) * 3 + c] : (half_t)0.f;
    }
    __syncthreads();

    // MFMA: 16 tasks (2 m-tiles x 8 n-sub-tiles) / 4 waves, K=288 (9 frags)
    #pragma unroll
    for (int i = 0; i < 4; ++i) {
        const int ti = wave + 4 * i;
        const int mt2 = ti >> 3, nt2 = ti & 7;
        const int c = nt * 128 + nt2 * 16 + m16;   // WGT' row
        f32x4 acc = (f32x4)(0.f);
        #pragma unroll
        for (int k = 0; k < 9; ++k) {
            half8 a = *(const half8*)&s_A[(mt2 * 16 + m16) * 296 + k * 32 + quad * 8];
            half8 bf = *(const half8*)&g_wf16[OFF_WGT + (size_t)c * 288 + k * 32 + quad * 8];
            acc = MFMA(a, bf, acc);
        }
        #pragma unroll
        for (int g = 0; g < 4; ++g)
            s_g[(mt2 * 16 + quad * 4 + g) * 136 + nt2 * 16 + m16] = (half_t)acc[g];
    }
    __syncthreads();

    // epilogue: 1024 outs / 256 thr
    float* h_next = g_hbuf + (size_t)(parity ^ 1) * 512 * 128 + (size_t)b * 32 * 128;
    #pragma unroll
    for (int e = 0; e < 4; ++e) {
        const int idx = tid + 256 * e;
        const int row = idx >> 5, jl = idx & 31;
        const int j = nt * 32 + jl;
        const float rs = (float)s_g[row * 136 + jl] + b_ir[j];
        const float is = (float)s_g[row * 136 + 32 + jl] + b_ii[j];
        const float ns = (float)s_g[row * 136 + 64 + jl] + b_in[j];
        const float hn = (float)s_g[row * 136 + 96 + jl];
        const float rr = 1.f / (1.f + __expf(-rs));
        const float ii = 1.f / (1.f + __expf(-is));
        const float nn = tanhf(ns + rr * hn);
        const float hold = hsrc[row * 128 + j];
        const float hnew = (1.f - ii) * nn + ii * hold;
        h_next[row * 128 + j] = hnew;
        const size_t grow = (size_t)b * 32 + row;
        out[(size_t)t * 512 * 128 + grow * 128 + j] = hnew;
        if (t == TSTEPS - 1)
            out[(size_t)TSTEPS * 512 * 128 + grow * 128 + j] = hnew;
    }
}

extern "C" void kernel_launch(void* const* d_in, const int* in_sizes, int n_in,
                              void* d_out, int out_size, void* d_ws, size_t ws_size,
                              hipStream_t stream) {
    const float* enc_in = (const float*)d_in[0];
    const float* dec_in = (const float*)d_in[1];
    // d_in[2], d_in[3] = R, S incidence: fully-connected, not needed.
    const float* enc_w1 = (const float*)d_in[4];
    const float* enc_b1 = (const float*)d_in[5];
    const float* enc_w2 = (const float*)d_in[6];
    const float* enc_b2 = (const float*)d_in[7];
    const float* pe_w1 = (const float*)d_in[8];
    const float* pe_b1 = (const float*)d_in[9];
    const float* pe_w2 = (const float*)d_in[10];
    const float* pe_b2 = (const float*)d_in[11];
    const float* pn_w1 = (const float*)d_in[12];
    const float* pn_b1 = (const float*)d_in[13];
    const float* pn_w2 = (const float*)d_in[14];
    const float* pn_b2 = (const float*)d_in[15];
    const float* de_w1 = (const float*)d_in[16];
    const float* de_b1 = (const float*)d_in[17];
    const float* de_w2 = (const float*)d_in[18];
    const float* de_b2 = (const float*)d_in[19];
    const float* w_hr = (const float*)d_in[20];
    const float* w_hi = (const float*)d_in[21];
    const float* w_hn = (const float*)d_in[22];
    const float* w_ir = (const float*)d_in[23];
    const float* b_ir = (const float*)d_in[24];
    const float* w_ii = (const float*)d_in[25];
    const float* b_ii = (const float*)d_in[26];
    const float* w_in = (const float*)d_in[27];
    const float* b_in = (const float*)d_in[28];
    (void)d_ws; (void)ws_size; (void)in_sizes; (void)n_in;

    convert_kernel<<<(WTOTAL + 255) / 256, 256, 0, stream>>>(
        enc_w1, enc_w2, pe_w1, pe_w2, pn_w1, pn_w2, de_w1, de_w2,
        w_hr, w_hi, w_hn, w_ir, w_ii, w_in);

    encoder_kernel<<<128, 512, 0, stream>>>(enc_in, enc_b1, enc_b2);

    int p = 0;
    for (int pass = 0; pass < 2; ++pass) {
        edge_kernel<0><<<512, 256, 0, stream>>>(p, pe_b1, pe_b2);
        node_kernel<<<32, 256, 0, stream>>>(p ^ 1, pn_b1, pn_b2);
        p ^= 1;
    }
    float* out = (float*)d_out;
    for (int t = 0; t < TSTEPS; ++t) {
        edge_kernel<1><<<512, 256, 0, stream>>>(p, de_b1, de_b2);
        gru_kernel<<<64, 256, 0, stream>>>(p, t, b_ir, b_ii, b_in, dec_in, out);
        p ^= 1;
    }
}